// Round 1
// baseline (4707.878 us; speedup 1.0000x reference)
//
#include <hip/hip_runtime.h>
#include <hip/hip_bf16.h>

#define BB 256
#define TT 512
#define HH 1024
#define CC 10

typedef __bf16 bf16x8 __attribute__((ext_vector_type(8)));
typedef float  f32x4  __attribute__((ext_vector_type(4)));

__device__ __forceinline__ float tanh_poly(float z) {
    // odd poly: z - z^3/3 + 2z^5/15 - 17z^7/315 ; |err| < 1e-5 for |z| <= 0.35
    float z2 = z * z;
    float c = fmaf(z2, fmaf(z2, fmaf(z2, -17.f / 315.f, 2.f / 15.f), -1.f / 3.f), 1.f);
    return z * c;
}

__global__ __launch_bounds__(256, 1)
void rnn_persistent(const float* __restrict__ x, const float* __restrict__ whx,
                    const float* __restrict__ whh, const float* __restrict__ bias_h,
                    const float* __restrict__ wph, const float* __restrict__ bias_p,
                    float* __restrict__ out, __bf16* hA, __bf16* hB, unsigned* ctr)
{
    __shared__ __bf16 hs[16 * 1032];   // h tile, rows padded to 1032 (2-way-free banks)
    __shared__ float  xs[TT * 16];     // x transposed: xs[t*16 + r]

    const int tid  = threadIdx.x;
    const int b    = blockIdx.x;
    const int xcd  = b & 7;
    const int kk   = b >> 3;
    const int group  = xcd * 2 + (kk >> 4);   // 0..15, members co-located per XCD (heuristic)
    const int member = kk & 15;               // 0..15
    const int rbase  = group * 16;

    const int wave = tid >> 6;
    const int lane = tid & 63;
    const int n    = lane & 15;               // B col / D col
    const int q    = lane >> 4;               // quad
    const int jbase = member * 64 + wave * 16;
    const int j     = jbase + n;

    // ---- stage x for our 16 rows, transposed into LDS ----
    for (int e = tid; e < 16 * TT; e += 256) {
        int r = e >> 9;            // TT = 512
        int t = e & (TT - 1);
        xs[t * 16 + r] = x[(size_t)(rbase + r) * TT + t];
    }

    // ---- load whh B-fragments into registers (fp32 -> bf16), 128 VGPRs/lane ----
    bf16x8 Bf[32];
    {
        const float* wrow = whh + (size_t)j * HH + q * 8;
        #pragma unroll
        for (int c = 0; c < 32; ++c) {
            const float* p = wrow + c * 32;
            bf16x8 v;
            #pragma unroll
            for (int u = 0; u < 8; ++u) v[u] = (__bf16)p[u];
            Bf[c] = v;
        }
    }
    const float whx_l = whx[j];
    const float bh_l  = bias_h[j];

    unsigned* ctr_g = ctr + group * 16;   // 64B-spaced counters

    __syncthreads();

    const int abase = n * 1032 + q * 8;   // A-frag LDS base (row = lane&15, koff = q*8)

    for (int s = 0; s < TT; ++s) {
        const __bf16* hc = (s & 1) ? hB : hA;
        __bf16*       hn = (s & 1) ? hA : hB;
        const __bf16* hcg = hc + (size_t)rbase * HH;

        // ---- stage h tile (32KB) -> LDS, padded rows ----
        #pragma unroll
        for (int it = 0; it < 8; ++it) {
            int e   = (it * 256 + tid) * 8;
            int row = e >> 10;
            int col = e & 1023;
            *(uint4*)&hs[row * 1032 + col] = *(const uint4*)&hcg[e];
        }
        __syncthreads();

        // ---- 16x64 output tile per wave-group: 32 MFMAs, 4 acc chains ----
        f32x4 acc[4];
        #pragma unroll
        for (int i = 0; i < 4; ++i) acc[i] = (f32x4){0.f, 0.f, 0.f, 0.f};
        #pragma unroll
        for (int c = 0; c < 32; ++c) {
            bf16x8 a = *(const bf16x8*)&hs[abase + c * 32];
            acc[c & 3] = __builtin_amdgcn_mfma_f32_16x16x32_bf16(a, Bf[c], acc[c & 3], 0, 0, 0);
        }
        f32x4 tot = (acc[0] + acc[1]) + (acc[2] + acc[3]);

        // ---- epilogue: z = dot + x_t*whx_j + bias; h = tanh(z); store bf16 ----
        #pragma unroll
        for (int i = 0; i < 4; ++i) {
            int r = q * 4 + i;                       // D row = (lane>>4)*4 + reg
            float z  = tot[i] + xs[s * 16 + r] * whx_l + bh_l;
            float hv = tanh_poly(z);
            hn[(size_t)(rbase + r) * HH + j] = (__bf16)hv;
        }

        // ---- group barrier (16 blocks), monotonic counter, agent scope ----
        __syncthreads();
        if (tid == 0) {
            __hip_atomic_fetch_add(ctr_g, 1u, __ATOMIC_RELEASE, __HIP_MEMORY_SCOPE_AGENT);
            const unsigned tgt = (unsigned)(16 * (s + 1));
            while (__hip_atomic_load(ctr_g, __ATOMIC_RELAXED, __HIP_MEMORY_SCOPE_AGENT) < tgt) {}
            (void)__hip_atomic_load(ctr_g, __ATOMIC_ACQUIRE, __HIP_MEMORY_SCOPE_AGENT);
        }
        __syncthreads();
    }

    // ---- final projection p = h_T @ wph^T + bias_p, by member 0 of each group ----
    // TT even -> final state is in hA
    if (member == 0 && tid < 16 * CC) {
        int r = tid / CC, c = tid % CC;
        const __bf16* hr = hA + (size_t)(rbase + r) * HH;
        const float*  wr = wph + (size_t)c * HH;
        float sum = 0.f;
        for (int jj = 0; jj < HH; jj += 8) {
            bf16x8 hv = *(const bf16x8*)&hr[jj];
            #pragma unroll
            for (int u = 0; u < 8; ++u) sum += (float)hv[u] * wr[jj + u];
        }
        out[(rbase + r) * CC + c] = sum + bias_p[c];
    }
}

extern "C" void kernel_launch(void* const* d_in, const int* in_sizes, int n_in,
                              void* d_out, int out_size, void* d_ws, size_t ws_size,
                              hipStream_t stream) {
    const float* x      = (const float*)d_in[0];
    const float* whx    = (const float*)d_in[1];
    const float* whh    = (const float*)d_in[2];
    const float* bias_h = (const float*)d_in[3];
    const float* wph    = (const float*)d_in[4];
    const float* bias_p = (const float*)d_in[5];
    float* out = (float*)d_out;

    unsigned* ctr = (unsigned*)d_ws;                       // 16 counters, 64B apart (first 1KB)
    __bf16* hA = (__bf16*)((char*)d_ws + 4096);            // 256*1024 bf16 = 512KB
    __bf16* hB = hA + BB * HH;                             // 512KB

    // zero counters + hA (h0 = 0); hB is write-before-read
    hipMemsetAsync(d_ws, 0, 4096 + (size_t)BB * HH * sizeof(__bf16), stream);

    rnn_persistent<<<dim3(256), dim3(256), 0, stream>>>(x, whx, whh, bias_h, wph, bias_p,
                                                        out, hA, hB, ctr);
}

// Round 2
// 3071.321 us; speedup vs baseline: 1.5329x; 1.5329x over previous
//
#include <hip/hip_runtime.h>
#include <hip/hip_bf16.h>

#define BB 256
#define TT 512
#define HH 1024
#define CC 10

typedef __bf16 bf16x8 __attribute__((ext_vector_type(8)));
typedef float  f32x4  __attribute__((ext_vector_type(4)));

__device__ __forceinline__ float tanh_poly(float z) {
    // odd poly: z - z^3/3 + 2z^5/15 - 17z^7/315 ; |err| < 1e-5 for |z| <= 0.35
    float z2 = z * z;
    float c = fmaf(z2, fmaf(z2, fmaf(z2, -17.f / 315.f, 2.f / 15.f), -1.f / 3.f), 1.f);
    return z * c;
}

__global__ __launch_bounds__(256, 1)
void rnn_persistent(const float* __restrict__ x, const float* __restrict__ whx,
                    const float* __restrict__ whh, const float* __restrict__ bias_h,
                    const float* __restrict__ wph, const float* __restrict__ bias_p,
                    float* __restrict__ out, __bf16* hA, __bf16* hB, unsigned* flags)
{
    __shared__ __bf16 hs[16 * 1032];   // h tile, rows padded (+8 elems keeps b128 16B-aligned)
    __shared__ float  xs[TT * 16];     // x transposed: xs[t*16 + r]

    const int tid = threadIdx.x;
    const int b   = blockIdx.x;
    const int xcd = b & 7;
    const int kk  = b >> 3;
    const int group  = xcd * 2 + (kk >> 4);   // 0..15 (members co-located per XCD heuristic)
    const int member = kk & 15;               // 0..15
    const int rbase  = group * 16;

    const int wave = tid >> 6;
    const int lane = tid & 63;
    const int n = lane & 15;                  // B col / D col
    const int q = lane >> 4;                  // quad
    const int j = member * 64 + wave * 16 + n;

    // ---- stage x for our 16 rows, transposed into LDS ----
    for (int e = tid; e < 16 * TT; e += 256) {
        int r = e >> 9, t = e & (TT - 1);
        xs[t * 16 + r] = x[(size_t)(rbase + r) * TT + t];
    }

    // ---- whh B-fragments into registers (fp32 -> bf16), 128 VGPRs/lane ----
    bf16x8 Bf[32];
    {
        const float* wrow = whh + (size_t)j * HH + q * 8;
        #pragma unroll
        for (int c = 0; c < 32; ++c) {
            const float* p = wrow + c * 32;
            bf16x8 v;
            #pragma unroll
            for (int u = 0; u < 8; ++u) v[u] = (__bf16)p[u];
            Bf[c] = v;
        }
    }
    const float whx_l = whx[j];
    const float bh_l  = bias_h[j];

    unsigned* fl = flags + group * 16;   // 16 epoch flags, one 64B line per group

    __syncthreads();

    const int abase = n * 1032 + q * 8;  // A-frag LDS base (row = lane&15, koff = q*8)

    for (int s = 0; s < TT; ++s) {
        // ---- wait until every member has posted h_s (flags[m] >= s) ----
        if (wave == 0) {
            const unsigned tgt = (unsigned)s;
            for (;;) {
                unsigned f = (lane < 16)
                    ? __hip_atomic_load(&fl[lane], __ATOMIC_RELAXED, __HIP_MEMORY_SCOPE_AGENT)
                    : tgt;
                if (__all(f >= tgt)) break;
            }
        }
        __syncthreads();

        // ---- read h_s tile (32 KB) via coherent (sc0+sc1) 8B loads -> LDS ----
        const __bf16* hc = ((s & 1) ? hB : hA) + (size_t)rbase * HH;
        #pragma unroll
        for (int i = 0; i < 16; ++i) {
            unsigned long long v = __hip_atomic_load(
                (unsigned long long*)(hc + ((size_t)i * 256 + tid) * 4),
                __ATOMIC_RELAXED, __HIP_MEMORY_SCOPE_AGENT);
            *(unsigned long long*)&hs[i * 1032 + tid * 4] = v;   // row=i, col=tid*4
        }
        __syncthreads();

        // ---- 16x64 tile per block: 32 MFMAs, 4 independent acc chains ----
        f32x4 acc[4];
        #pragma unroll
        for (int i = 0; i < 4; ++i) acc[i] = (f32x4){0.f, 0.f, 0.f, 0.f};
        #pragma unroll
        for (int c = 0; c < 32; ++c) {
            bf16x8 a = *(const bf16x8*)&hs[abase + c * 32];
            acc[c & 3] = __builtin_amdgcn_mfma_f32_16x16x32_bf16(a, Bf[c], acc[c & 3], 0, 0, 0);
        }
        f32x4 tot = (acc[0] + acc[1]) + (acc[2] + acc[3]);

        // ---- epilogue: z = dot + x_t*whx_j + bias; h = tanh(z); coherent bf16 store ----
        __bf16* hn = (s & 1) ? hA : hB;
        #pragma unroll
        for (int i = 0; i < 4; ++i) {
            int r = q * 4 + i;                     // D row = (lane>>4)*4 + reg
            float z  = tot[i] + xs[s * 16 + r] * whx_l + bh_l;
            unsigned short hv = __builtin_bit_cast(unsigned short, (__bf16)tanh_poly(z));
            __hip_atomic_store((unsigned short*)&hn[(size_t)(rbase + r) * HH + j], hv,
                               __ATOMIC_RELAXED, __HIP_MEMORY_SCOPE_AGENT);
        }

        // ---- publish: drain stores to coherence point, then post epoch flag ----
        asm volatile("s_waitcnt vmcnt(0)" ::: "memory");
        __syncthreads();
        if (tid == 0)
            __hip_atomic_store(&fl[member], (unsigned)(s + 1),
                               __ATOMIC_RELAXED, __HIP_MEMORY_SCOPE_AGENT);
    }

    // ---- wait for h_T complete, then projection p = h_T @ wph^T + bias_p ----
    if (wave == 0) {
        for (;;) {
            unsigned f = (lane < 16)
                ? __hip_atomic_load(&fl[lane], __ATOMIC_RELAXED, __HIP_MEMORY_SCOPE_AGENT)
                : (unsigned)TT;
            if (__all(f >= (unsigned)TT)) break;
        }
    }
    __syncthreads();

    if (member == 0 && tid < 16 * CC) {
        int r = tid / CC, c = tid % CC;
        const __bf16* hr = hA + (size_t)(rbase + r) * HH;   // TT even -> final state in hA
        const float*  wr = wph + (size_t)c * HH;
        float sum = 0.f;
        for (int jj = 0; jj < HH; jj += 4) {
            unsigned long long v = __hip_atomic_load(
                (unsigned long long*)(hr + jj), __ATOMIC_RELAXED, __HIP_MEMORY_SCOPE_AGENT);
            bf16x8 hv4;
            *(unsigned long long*)&hv4 = v;   // low 4 lanes valid
            #pragma unroll
            for (int u = 0; u < 4; ++u) sum += (float)hv4[u] * wr[jj + u];
        }
        out[(rbase + r) * CC + c] = sum + bias_p[c];
    }
}

extern "C" void kernel_launch(void* const* d_in, const int* in_sizes, int n_in,
                              void* d_out, int out_size, void* d_ws, size_t ws_size,
                              hipStream_t stream) {
    const float* x      = (const float*)d_in[0];
    const float* whx    = (const float*)d_in[1];
    const float* whh    = (const float*)d_in[2];
    const float* bias_h = (const float*)d_in[3];
    const float* wph    = (const float*)d_in[4];
    const float* bias_p = (const float*)d_in[5];
    float* out = (float*)d_out;

    unsigned* flags = (unsigned*)d_ws;                     // 16 groups x 16 dwords = 1KB
    __bf16* hA = (__bf16*)((char*)d_ws + 4096);            // 512KB
    __bf16* hB = hA + BB * HH;                             // 512KB

    // zero flags + hA (h0 = 0); hB is write-before-read
    hipMemsetAsync(d_ws, 0, 4096 + (size_t)BB * HH * sizeof(__bf16), stream);

    rnn_persistent<<<dim3(256), dim3(256), 0, stream>>>(x, whx, whh, bias_h, wph, bias_p,
                                                        out, hA, hB, flags);
}